// Round 4
// baseline (6766.845 us; speedup 1.0000x reference)
//
#include <hip/hip_runtime.h>
#include <math.h>

#define B_  64
#define N_  512
#define H_  1024
#define NH_ 8
#define HD_ 128
#define S_  24

// ---------------------------------------------------------------------------
// Precompute (once per launch, fused):
//   W2[n][0..1023]      = 0.5*Wqt[n][k]
//   W2[n][1024+k]       = 0.5*(Wqt·Wout)[n][k]
//   bc[n]               = 0.5*dot(Wqt[n,:], bout) + bqt[n]
//   cnts[0..32]         = 0   (completion counters: 32 gates groups + 1 logits)
// 256 blocks x 256 threads: 16x16 grid of 64x64 tiles for the GEMM part.
// ---------------------------------------------------------------------------
__global__ __launch_bounds__(256) void wc_pre(
    const float* __restrict__ Wqt, const float* __restrict__ Wout,
    const float* __restrict__ bout, const float* __restrict__ bqt,
    float* __restrict__ W2, float* __restrict__ bc,
    unsigned* __restrict__ cnts)
{
  if (blockIdx.x == 0 && threadIdx.x < 33) cnts[threadIdx.x] = 0u;

  __shared__ float As[16][68];   // [m][n] of Wqt tile (transposed stage)
  __shared__ float Bs[16][68];   // [m][k] of Wout tile
  const int tid = threadIdx.x;
  const int k0 = (blockIdx.x & 15) * 64;
  const int n0 = (blockIdx.x >> 4) * 64;
  const int tn = tid & 15, tm = tid >> 4;

  // copy half: W2[n][k] = 0.5*Wqt[n][k]
#pragma unroll
  for (int i = 0; i < 4; ++i) {
    int n = n0 + tm * 4 + i;
    float4 w = *(const float4*)(Wqt + (size_t)n * 1024 + k0 + tn * 4);
    *(float4*)(W2 + (size_t)n * 2048 + k0 + tn * 4) =
        make_float4(0.5f * w.x, 0.5f * w.y, 0.5f * w.z, 0.5f * w.w);
  }

  float acc[4][4];
#pragma unroll
  for (int i = 0; i < 4; ++i)
#pragma unroll
    for (int j = 0; j < 4; ++j) acc[i][j] = 0.f;

  for (int m0 = 0; m0 < 1024; m0 += 16) {
    {
      int nn = tid >> 2, mm = (tid & 3) * 4;
      float4 a = *(const float4*)(Wqt + (size_t)(n0 + nn) * 1024 + m0 + mm);
      As[mm + 0][nn] = a.x; As[mm + 1][nn] = a.y;
      As[mm + 2][nn] = a.z; As[mm + 3][nn] = a.w;
      int mr = tid >> 4, kc = (tid & 15) * 4;
      float4 b = *(const float4*)(Wout + (size_t)(m0 + mr) * 1024 + k0 + kc);
      *(float4*)(&Bs[mr][kc]) = b;
    }
    __syncthreads();
#pragma unroll
    for (int m = 0; m < 16; ++m) {
      float av[4], bv[4];
      *(float4*)av = *(const float4*)(&As[m][tm * 4]);
      *(float4*)bv = *(const float4*)(&Bs[m][tn * 4]);
#pragma unroll
      for (int i = 0; i < 4; ++i)
#pragma unroll
        for (int j = 0; j < 4; ++j)
          acc[i][j] = fmaf(av[i], bv[j], acc[i][j]);
    }
    __syncthreads();
  }
#pragma unroll
  for (int i = 0; i < 4; ++i) {
    int n = n0 + tm * 4 + i;
    *(float4*)(W2 + (size_t)n * 2048 + 1024 + k0 + tn * 4) =
        make_float4(0.5f * acc[i][0], 0.5f * acc[i][1],
                    0.5f * acc[i][2], 0.5f * acc[i][3]);
  }

  // bc part (independent; wave per n, 4 n per block)
  {
    int w = tid >> 6, lane = tid & 63;
    int n = blockIdx.x * 4 + w;
    const float* row = Wqt + (size_t)n * 1024;
    float s = 0.f;
#pragma unroll
    for (int c = 0; c < 4; ++c) {
      float4 a = *(const float4*)(row + lane * 16 + c * 4);
      float4 b = *(const float4*)(bout + lane * 16 + c * 4);
      s = fmaf(a.x, b.x, fmaf(a.y, b.y, fmaf(a.z, b.z, fmaf(a.w, b.w, s))));
    }
#pragma unroll
    for (int off = 32; off > 0; off >>= 1) s += __shfl_down(s, off, 64);
    if (lane == 0) bc[n] = 0.5f * s + bqt[n];
  }
}

__device__ __forceinline__ float sigm(float x) { return 1.f / (1.f + expf(-x)); }

__device__ __forceinline__ void ins3(float v, int i,
    float& v0, int& i0, float& v1, int& i1, float& v2, int& i2)
{
  if (v > v0 || (v == v0 && i < i0)) {
    v2 = v1; i2 = i1; v1 = v0; i1 = i0; v0 = v; i0 = i;
  } else if (v > v1 || (v == v1 && i < i1)) {
    v2 = v1; i2 = i1; v1 = v; i1 = i;
  } else if (v > v2 || (v == v2 && i < i2)) {
    v2 = v; i2 = i;
  }
}

// ---------------------------------------------------------------------------
// Gates GEMM + fused LSTM reduce (last-block-per-group pattern).
// Grid (32 nb, 8 sp) x 512 thr.  Output cols of group nb are gate-aligned:
// local col c (0..127) -> W row (c>>5)*1024 + nb*32 + (c&31), so one nb group
// owns all 4 gates of 32 h-columns.  After all 8 split-K blocks of group nb
// complete (per-nb counter, monotonic across steps), the last block reduces
// the 8 partials + biases and applies the LSTM pointwise for its 32 columns.
// h is ping-ponged by the caller (this kernel reads h_prev, writes h_out).
// c is touched only here, on disjoint 32-col slices (in-place safe).
// ---------------------------------------------------------------------------
__global__ __launch_bounds__(512, 2) void gemm_gates(
    const float* __restrict__ x0, const float* __restrict__ h_prev,
    const float* __restrict__ W_ih, const float* __restrict__ W_hh,
    const float* __restrict__ enc, const int* __restrict__ idxi, int gather,
    const float* __restrict__ b_ih, const float* __restrict__ b_hh,
    const float* __restrict__ c_in, float* __restrict__ c_out,
    float* __restrict__ h_out, float* __restrict__ P,
    unsigned* __restrict__ cnt, int step)
{
  __shared__ float As[16 * 68];
  __shared__ float Bs[16 * 132];
  __shared__ int amLast;
  const int tid = threadIdx.x;
  const int nb = blockIdx.x, sp = blockIdx.y;
  const int ks = sp * 512;

  const float* A; const float* W; int ldA, ldW, koff; int seg0;
  if (ks < 3072) { W = W_ih; ldW = 3072; koff = ks; A = x0;     ldA = 3072; seg0 = 1; }
  else           { W = W_hh; ldW = 1024; koff = ks - 3072; A = h_prev; ldA = 1024; seg0 = 0; }

  const int tn = tid & 31, tm = tid >> 5;
  const int lr = tid >> 2, lc = (tid & 3) * 4;

  float acc[4][4];
#pragma unroll
  for (int i = 0; i < 4; ++i)
#pragma unroll
    for (int j = 0; j < 4; ++j) acc[i][j] = 0.f;

  // gate-aligned W row for local col lr
  const int wrow = (lr >> 5) * 1024 + nb * 32 + (lr & 31);
  const float* Wrow = W + (size_t)wrow * ldW + koff + lc;
  const float* Arow = nullptr;
  if (tid < 256) {
    if (seg0 && gather) {
      int ei = idxi[lr * 3 + (koff >> 10)];
      Arow = enc + ((size_t)lr * 512 + ei) * 1024 + (koff & 1023) + lc;
    } else {
      Arow = A + (size_t)lr * ldA + koff + lc;
    }
  }

  for (int k0 = 0; k0 < 512; k0 += 16) {
    float4 b4 = *(const float4*)(Wrow + k0);
    if (tid < 256) {
      float4 a4 = *(const float4*)(Arow + k0);
      As[(lc + 0) * 68 + lr] = a4.x; As[(lc + 1) * 68 + lr] = a4.y;
      As[(lc + 2) * 68 + lr] = a4.z; As[(lc + 3) * 68 + lr] = a4.w;
    }
    Bs[(lc + 0) * 132 + lr] = b4.x; Bs[(lc + 1) * 132 + lr] = b4.y;
    Bs[(lc + 2) * 132 + lr] = b4.z; Bs[(lc + 3) * 132 + lr] = b4.w;
    __syncthreads();
#pragma unroll
    for (int k = 0; k < 16; ++k) {
      float av[4], bv[4];
      *(float4*)av = *(const float4*)(As + k * 68 + tm * 4);
      *(float4*)bv = *(const float4*)(Bs + k * 132 + tn * 4);
#pragma unroll
      for (int i = 0; i < 4; ++i)
#pragma unroll
        for (int j = 0; j < 4; ++j)
          acc[i][j] = fmaf(av[i], bv[j], acc[i][j]);
    }
    __syncthreads();
  }
  float* Pb = P + (size_t)sp * 64 * 4096 + nb * 128;
#pragma unroll
  for (int i = 0; i < 4; ++i)
    *(float4*)(Pb + (size_t)(tm * 4 + i) * 4096 + tn * 4) =
        make_float4(acc[i][0], acc[i][1], acc[i][2], acc[i][3]);

  // ---- completion: last of 8 split-K blocks does the LSTM for this group ----
  __threadfence();                         // release partials (device scope)
  __syncthreads();
  if (tid == 0) {
    unsigned old = atomicAdd(&cnt[nb], 1u);
    amLast = (old == (unsigned)(step * 8 + 7));
  }
  __syncthreads();
  if (!amLast) return;
  __threadfence();                         // acquire others' partials

  const int b = tid >> 3, j4 = (tid & 7) * 4;     // 64 b x 8 j4-groups
  const int jg = nb * 32 + j4;
  float g[4][4];
#pragma unroll
  for (int gi = 0; gi < 4; ++gi) {
    float4 s  = *(const float4*)(b_ih + gi * 1024 + jg);
    float4 s2 = *(const float4*)(b_hh + gi * 1024 + jg);
    s.x += s2.x; s.y += s2.y; s.z += s2.z; s.w += s2.w;
    const int lcb = nb * 128 + gi * 32 + j4;
#pragma unroll
    for (int spp = 0; spp < 8; ++spp) {
      float4 v = *(const float4*)(P + ((size_t)spp * 64 + b) * 4096 + lcb);
      s.x += v.x; s.y += v.y; s.z += v.z; s.w += v.w;
    }
    g[gi][0] = s.x; g[gi][1] = s.y; g[gi][2] = s.z; g[gi][3] = s.w;
  }
  float4 cp = *(const float4*)(c_in + b * 1024 + jg);
  float cv[4] = {cp.x, cp.y, cp.z, cp.w};
  float4 ho, co; float* hp = &ho.x; float* cpn = &co.x;
#pragma unroll
  for (int e = 0; e < 4; ++e) {
    float c = sigm(g[1][e]) * cv[e] + sigm(g[0][e]) * tanhf(g[2][e]);
    cpn[e] = c; hp[e] = sigm(g[3][e]) * tanhf(c);
  }
  *(float4*)(c_out + b * 1024 + jg) = co;
  *(float4*)(h_out + b * 1024 + jg) = ho;
}

// ---------------------------------------------------------------------------
// Split-K GEMM (unchanged): P[sp][64][N] = A[64,Kslice] @ W[N,Kslice]^T
// ---------------------------------------------------------------------------
__global__ __launch_bounds__(512, 2) void gemm5(
    const float* __restrict__ A0, int ldA0, const float* __restrict__ W0, int ldW0,
    int K0,
    const float* __restrict__ A1, int ldA1, const float* __restrict__ W1, int ldW1,
    float* __restrict__ P, int N, int KS)
{
  __shared__ float As[16 * 68];
  __shared__ float Bs[16 * 132];
  const int tid = threadIdx.x;
  const int nb = blockIdx.x, sp = blockIdx.y;
  const int ks = sp * KS;

  const float* A; const float* W; int ldA, ldW, koff;
  if (ks < K0) { A = A0; W = W0; ldA = ldA0; ldW = ldW0; koff = ks; }
  else { A = A1; W = W1; ldA = ldA1; ldW = ldW1; koff = ks - K0; }

  const int tn = tid & 31, tm = tid >> 5;
  const int lr = tid >> 2, lc = (tid & 3) * 4;

  float acc[4][4];
#pragma unroll
  for (int i = 0; i < 4; ++i)
#pragma unroll
    for (int j = 0; j < 4; ++j) acc[i][j] = 0.f;

  const float* Wrow = W + (size_t)(nb * 128 + lr) * ldW + koff + lc;
  const float* Arow = (tid < 256) ? A + (size_t)lr * ldA + koff + lc : nullptr;

  for (int k0 = 0; k0 < KS; k0 += 16) {
    float4 b4 = *(const float4*)(Wrow + k0);
    if (tid < 256) {
      float4 a4 = *(const float4*)(Arow + k0);
      As[(lc + 0) * 68 + lr] = a4.x; As[(lc + 1) * 68 + lr] = a4.y;
      As[(lc + 2) * 68 + lr] = a4.z; As[(lc + 3) * 68 + lr] = a4.w;
    }
    Bs[(lc + 0) * 132 + lr] = b4.x; Bs[(lc + 1) * 132 + lr] = b4.y;
    Bs[(lc + 2) * 132 + lr] = b4.z; Bs[(lc + 3) * 132 + lr] = b4.w;
    __syncthreads();
#pragma unroll
    for (int k = 0; k < 16; ++k) {
      float av[4], bv[4];
      *(float4*)av = *(const float4*)(As + k * 68 + tm * 4);
      *(float4*)bv = *(const float4*)(Bs + k * 132 + tn * 4);
#pragma unroll
      for (int i = 0; i < 4; ++i)
#pragma unroll
        for (int j = 0; j < 4; ++j)
          acc[i][j] = fmaf(av[i], bv[j], acc[i][j]);
    }
    __syncthreads();
  }
  float* Pb = P + (size_t)sp * 64 * N + nb * 128;
#pragma unroll
  for (int i = 0; i < 4; ++i)
    *(float4*)(Pb + (size_t)(tm * 4 + i) * N + tn * 4) =
        make_float4(acc[i][0], acc[i][1], acc[i][2], acc[i][3]);
}

// ---------------------------------------------------------------------------
// Attention with fused qkv-partial reduce. 512 blocks (b,h) x 128 threads.
// ---------------------------------------------------------------------------
__global__ __launch_bounds__(128) void attn_fused(
    const float* __restrict__ P, const float* __restrict__ bqkv,
    float* __restrict__ Kc, float* __restrict__ Vc,
    float* __restrict__ ctx, int t)
{
  const float scale = 0.08838834764831845f;  // 1/sqrt(128)
  int bh = blockIdx.x;
  int b = bh >> 3, h = bh & 7;
  int d = threadIdx.x;
  __shared__ float qs[128];
  __shared__ float sc[S_];

  const float* Pb = P + (size_t)b * 3072 + h * 128 + d;
  float qv = bqkv[h * 128 + d];
  float kv = bqkv[1024 + h * 128 + d];
  float vv = bqkv[2048 + h * 128 + d];
#pragma unroll
  for (int sp = 0; sp < 8; ++sp) {
    const float* pp = Pb + (size_t)sp * 64 * 3072;
    qv += pp[0]; kv += pp[1024]; vv += pp[2048];
  }
  float* Kb = Kc + (size_t)(b * NH_ + h) * S_ * HD_;
  float* Vb = Vc + (size_t)(b * NH_ + h) * S_ * HD_;
  Kb[t * 128 + d] = kv;
  Vb[t * 128 + d] = vv;
  qs[d] = qv;
  __syncthreads();

  int wave = d >> 6, lane = d & 63;
  for (int s = wave; s <= t; s += 2) {
    float pr = qs[lane] * Kb[s * 128 + lane] + qs[lane + 64] * Kb[s * 128 + lane + 64];
#pragma unroll
    for (int off = 32; off > 0; off >>= 1) pr += __shfl_down(pr, off, 64);
    if (lane == 0) sc[s] = pr * scale;
  }
  __syncthreads();

  float m = -3.4e38f;
  for (int s = 0; s <= t; ++s) m = fmaxf(m, sc[s]);
  float den = 0.f;
  for (int s = 0; s <= t; ++s) den += expf(sc[s] - m);
  float acc = 0.f;
  for (int s = 0; s <= t; ++s) acc += expf(sc[s] - m) * Vb[s * 128 + d];
  ctx[(size_t)b * 1024 + h * 128 + d] = acc / den;
}

// ---------------------------------------------------------------------------
// logits3 + fused top3 merge (last-block pattern).
// 512 blocks (b, 64-row chunk) x 512 thr.  Stage q[b] (reduce 16 split-K
// partials + bias) into LDS, then 8 waves x 8 rows with float4 enc loads,
// butterfly reduce, per-wave top3 -> per-block candidate triple.  The last
// block to finish merges all 512 triples and writes idxi + idx_out.
// ---------------------------------------------------------------------------
__global__ __launch_bounds__(512) void logits3(
    const float* __restrict__ P, const float* __restrict__ bc,
    const float* __restrict__ enc, float* __restrict__ out,
    float* __restrict__ candv, int* __restrict__ candi,
    unsigned* __restrict__ cntL, int step,
    int* __restrict__ idxi, float* __restrict__ idx_out)
{
  __shared__ float qs[1024];
  __shared__ float cv[24];
  __shared__ int   ci[24];
  __shared__ int   amLast;
  const int tid = threadIdx.x;
  const int b = blockIdx.x >> 3, ng = blockIdx.x & 7;

  // stage q[b][0..1023] with fused split-K reduce (+bc)
  if (tid < 256) {
    const int j4 = tid * 4;
    float4 s = *(const float4*)(bc + j4);
#pragma unroll
    for (int sp = 0; sp < 16; ++sp) {
      float4 v = *(const float4*)(P + ((size_t)sp * 64 + b) * 1024 + j4);
      s.x += v.x; s.y += v.y; s.z += v.z; s.w += v.w;
    }
    *(float4*)(qs + j4) = s;
  }
  __syncthreads();

  const int wave = tid >> 6, lane = tid & 63;
  float4 q0 = *(const float4*)(qs + lane * 4);
  float4 q1 = *(const float4*)(qs + 256 + lane * 4);
  float4 q2 = *(const float4*)(qs + 512 + lane * 4);
  float4 q3 = *(const float4*)(qs + 768 + lane * 4);

  const int row0 = ng * 64 + wave * 8;            // 8 rows per wave
  const float* eb = enc + ((size_t)b * N_ + row0) * 1024 + lane * 4;
  float* lo = out + (size_t)b * N_ + row0;
  float v0 = -3.4e38f, v1 = -3.4e38f, v2 = -3.4e38f;
  int i0 = 0x7fffffff, i1 = 0x7fffffff, i2 = 0x7fffffff;
  float myout = 0.f;
#pragma unroll 4
  for (int r = 0; r < 8; ++r) {
    const float* e = eb + (size_t)r * 1024;
    float4 e0 = *(const float4*)(e);
    float4 e1 = *(const float4*)(e + 256);
    float4 e2 = *(const float4*)(e + 512);
    float4 e3 = *(const float4*)(e + 768);
    float s = 0.f;
    s = fmaf(q0.x, e0.x, s); s = fmaf(q0.y, e0.y, s);
    s = fmaf(q0.z, e0.z, s); s = fmaf(q0.w, e0.w, s);
    s = fmaf(q1.x, e1.x, s); s = fmaf(q1.y, e1.y, s);
    s = fmaf(q1.z, e1.z, s); s = fmaf(q1.w, e1.w, s);
    s = fmaf(q2.x, e2.x, s); s = fmaf(q2.y, e2.y, s);
    s = fmaf(q2.z, e2.z, s); s = fmaf(q2.w, e2.w, s);
    s = fmaf(q3.x, e3.x, s); s = fmaf(q3.y, e3.y, s);
    s = fmaf(q3.z, e3.z, s); s = fmaf(q3.w, e3.w, s);
#pragma unroll
    for (int off = 32; off > 0; off >>= 1) s += __shfl_xor(s, off, 64);
    if (lane == r) myout = s;
    ins3(s, row0 + r, v0, i0, v1, i1, v2, i2);
  }
  if (lane < 8) lo[lane] = myout;
  if (lane == 0) {
    cv[wave * 3 + 0] = v0; ci[wave * 3 + 0] = i0;
    cv[wave * 3 + 1] = v1; ci[wave * 3 + 1] = i1;
    cv[wave * 3 + 2] = v2; ci[wave * 3 + 2] = i2;
  }
  __syncthreads();
  if (tid == 0) {
    float w0 = -3.4e38f, w1 = -3.4e38f, w2 = -3.4e38f;
    int j0 = 0x7fffffff, j1 = 0x7fffffff, j2 = 0x7fffffff;
#pragma unroll
    for (int k = 0; k < 24; ++k)
      ins3(cv[k], ci[k], w0, j0, w1, j1, w2, j2);
    candv[blockIdx.x * 3 + 0] = w0; candi[blockIdx.x * 3 + 0] = j0;
    candv[blockIdx.x * 3 + 1] = w1; candi[blockIdx.x * 3 + 1] = j1;
    candv[blockIdx.x * 3 + 2] = w2; candi[blockIdx.x * 3 + 2] = j2;
  }

  // ---- last block merges all 512 candidate triples ----
  __threadfence();
  __syncthreads();
  if (tid == 0) {
    unsigned old = atomicAdd(cntL, 1u);
    amLast = (old == (unsigned)(step * 512 + 511));
  }
  __syncthreads();
  if (!amLast) return;
  __threadfence();
  if (tid < 64) {
    const int bb_ = tid;
    float w0 = -3.4e38f, w1 = -3.4e38f, w2 = -3.4e38f;
    int j0 = 0x7fffffff, j1 = 0x7fffffff, j2 = 0x7fffffff;
#pragma unroll
    for (int q = 0; q < 8; ++q) {
      int base = (bb_ * 8 + q) * 3;
#pragma unroll
      for (int k = 0; k < 3; ++k)
        ins3(candv[base + k], candi[base + k], w0, j0, w1, j1, w2, j2);
    }
    int a = j0, bb = j1, c = j2, tw;
    if (a > bb) { tw = a; a = bb; bb = tw; }
    if (bb > c) { tw = bb; bb = c; c = tw; }
    if (a > bb) { tw = a; a = bb; bb = tw; }
    idxi[bb_ * 3 + 0] = a; idxi[bb_ * 3 + 1] = bb; idxi[bb_ * 3 + 2] = c;
    float* io = idx_out + bb_ * 3;
    io[0] = (float)a; io[1] = (float)bb; io[2] = (float)c;
  }
}

// ---------------------------------------------------------------------------
extern "C" void kernel_launch(void* const* d_in, const int* in_sizes, int n_in,
                              void* d_out, int out_size, void* d_ws, size_t ws_size,
                              hipStream_t stream)
{
  (void)in_sizes; (void)n_in; (void)out_size; (void)ws_size;
  const float* enc   = (const float*)d_in[0];
  const float* h0    = (const float*)d_in[1];
  const float* c0    = (const float*)d_in[2];
  const float* x0    = (const float*)d_in[4];
  const float* W_ih  = (const float*)d_in[6];
  const float* b_ih  = (const float*)d_in[7];
  const float* W_hh  = (const float*)d_in[8];
  const float* b_hh  = (const float*)d_in[9];
  const float* Wqkv  = (const float*)d_in[10];
  const float* bqkv  = (const float*)d_in[11];
  const float* Wout  = (const float*)d_in[12];
  const float* bout  = (const float*)d_in[13];
  const float* Wqt   = (const float*)d_in[14];
  const float* bqt   = (const float*)d_in[15];

  float* ws    = (float*)d_ws;
  float* P     = ws;                          // 8*64*4096 floats
  float* W2    = P + 8 * 64 * 4096;           // 1024*2048
  float* bc    = W2 + 1024 * 2048;            // 1024
  float* hbuf  = bc + 1024;                   // 64*1024  (h ping)
  float* hbuf2 = hbuf + 64 * 1024;            // 64*1024  (h pong)
  float* cbuf  = hbuf2 + 64 * 1024;           // 64*1024
  float* ctx   = cbuf + 64 * 1024;            // 64*1024
  float* Kc    = ctx + 64 * 1024;             // 64*8*24*128
  float* Vc    = Kc + 64 * NH_ * S_ * HD_;
  float* candv = Vc + 64 * NH_ * S_ * HD_;    // 512*3
  int*   candi = (int*)(candv + 512 * 3);     // 512*3
  int*   idxi  = candi + 512 * 3;             // 192
  unsigned* cnt = (unsigned*)(idxi + 192);    // 33: [0..31] gates, [32] logits

  float* logits_out = (float*)d_out;                     // [S,B,N]
  float* idx_out    = logits_out + (size_t)S_ * B_ * N_; // [S,B,3] as float

  // once per launch: combined qt weights/bias + counter zeroing
  wc_pre<<<dim3(256), dim3(256), 0, stream>>>(Wqt, Wout, bout, bqt, W2, bc, cnt);

  for (int t = 0; t < S_; ++t) {
    float* hnew = (t & 1) ? hbuf2 : hbuf;
    const float* hprev = (t == 0) ? h0 : ((t & 1) ? hbuf : hbuf2);
    const float* cprev = (t == 0) ? c0 : cbuf;

    // gates GEMM + fused LSTM -> hnew, cbuf
    gemm_gates<<<dim3(32, 8), dim3(512), 0, stream>>>(
        x0, hprev, W_ih, W_hh, enc, idxi, t > 0,
        b_ih, b_hh, cprev, cbuf, hnew, P, cnt, t);

    // qkv = h @ Wqkv^T -> P[8][64][3072]
    gemm5<<<dim3(24, 8), dim3(512), 0, stream>>>(
        hnew, 1024, Wqkv, 1024, 1024,
        hnew, 1024, Wqkv, 1024,
        P, 3072, 128);
    attn_fused<<<dim3(512), dim3(128), 0, stream>>>(P, bqkv, Kc, Vc, ctx, t);

    // query = [h|ctx] @ W2^T (+bc at reduce) -> P[16][64][1024]
    gemm5<<<dim3(8, 16), dim3(512), 0, stream>>>(
        hnew, 1024, W2, 2048, 1024,
        ctx, 1024, W2 + 1024, 2048,
        P, 1024, 128);

    // logits + top3 (fused merge in last block)
    logits3<<<dim3(512), dim3(512), 0, stream>>>(
        P, bc, enc, logits_out + (size_t)t * B_ * N_, candv, candi,
        cnt + 32, t, idxi, idx_out + (size_t)t * B_ * 3);
  }
}

// Round 5
// 5123.956 us; speedup vs baseline: 1.3206x; 1.3206x over previous
//
#include <hip/hip_runtime.h>
#include <math.h>

#define B_  64
#define N_  512
#define H_  1024
#define NH_ 8
#define HD_ 128
#define S_  24

// ---------------------------------------------------------------------------
// Precompute (once per launch, fused):
//   W2[n][0..1023] = 0.5*Wqt[n][k];  W2[n][1024+k] = 0.5*(Wqt·Wout)[n][k]
//   bc[n] = 0.5*dot(Wqt[n,:], bout) + bqt[n]
// 256 blocks x 256 threads: 16x16 grid of 64x64 tiles.
// ---------------------------------------------------------------------------
__global__ __launch_bounds__(256) void wc_pre(
    const float* __restrict__ Wqt, const float* __restrict__ Wout,
    const float* __restrict__ bout, const float* __restrict__ bqt,
    float* __restrict__ W2, float* __restrict__ bc)
{
  __shared__ float As[16][68];   // [m][n] of Wqt tile (transposed stage)
  __shared__ float Bs[16][68];   // [m][k] of Wout tile
  const int tid = threadIdx.x;
  const int k0 = (blockIdx.x & 15) * 64;
  const int n0 = (blockIdx.x >> 4) * 64;
  const int tn = tid & 15, tm = tid >> 4;

  // copy half: W2[n][k] = 0.5*Wqt[n][k]
#pragma unroll
  for (int i = 0; i < 4; ++i) {
    int n = n0 + tm * 4 + i;
    float4 w = *(const float4*)(Wqt + (size_t)n * 1024 + k0 + tn * 4);
    *(float4*)(W2 + (size_t)n * 2048 + k0 + tn * 4) =
        make_float4(0.5f * w.x, 0.5f * w.y, 0.5f * w.z, 0.5f * w.w);
  }

  float acc[4][4];
#pragma unroll
  for (int i = 0; i < 4; ++i)
#pragma unroll
    for (int j = 0; j < 4; ++j) acc[i][j] = 0.f;

  for (int m0 = 0; m0 < 1024; m0 += 16) {
    {
      int nn = tid >> 2, mm = (tid & 3) * 4;
      float4 a = *(const float4*)(Wqt + (size_t)(n0 + nn) * 1024 + m0 + mm);
      As[mm + 0][nn] = a.x; As[mm + 1][nn] = a.y;
      As[mm + 2][nn] = a.z; As[mm + 3][nn] = a.w;
      int mr = tid >> 4, kc = (tid & 15) * 4;
      float4 b = *(const float4*)(Wout + (size_t)(m0 + mr) * 1024 + k0 + kc);
      *(float4*)(&Bs[mr][kc]) = b;
    }
    __syncthreads();
#pragma unroll
    for (int m = 0; m < 16; ++m) {
      float av[4], bv[4];
      *(float4*)av = *(const float4*)(&As[m][tm * 4]);
      *(float4*)bv = *(const float4*)(&Bs[m][tn * 4]);
#pragma unroll
      for (int i = 0; i < 4; ++i)
#pragma unroll
        for (int j = 0; j < 4; ++j)
          acc[i][j] = fmaf(av[i], bv[j], acc[i][j]);
    }
    __syncthreads();
  }
#pragma unroll
  for (int i = 0; i < 4; ++i) {
    int n = n0 + tm * 4 + i;
    *(float4*)(W2 + (size_t)n * 2048 + 1024 + k0 + tn * 4) =
        make_float4(0.5f * acc[i][0], 0.5f * acc[i][1],
                    0.5f * acc[i][2], 0.5f * acc[i][3]);
  }

  // bc part (independent; wave per n, 4 n per block)
  {
    int w = tid >> 6, lane = tid & 63;
    int n = blockIdx.x * 4 + w;
    const float* row = Wqt + (size_t)n * 1024;
    float s = 0.f;
#pragma unroll
    for (int c = 0; c < 4; ++c) {
      float4 a = *(const float4*)(row + lane * 16 + c * 4);
      float4 b = *(const float4*)(bout + lane * 16 + c * 4);
      s = fmaf(a.x, b.x, fmaf(a.y, b.y, fmaf(a.z, b.z, fmaf(a.w, b.w, s))));
    }
#pragma unroll
    for (int off = 32; off > 0; off >>= 1) s += __shfl_down(s, off, 64);
    if (lane == 0) bc[n] = 0.5f * s + bqt[n];
  }
}

__device__ __forceinline__ float sigm(float x) { return 1.f / (1.f + expf(-x)); }

__device__ __forceinline__ void ins3(float v, int i,
    float& v0, int& i0, float& v1, int& i1, float& v2, int& i2)
{
  if (v > v0 || (v == v0 && i < i0)) {
    v2 = v1; i2 = i1; v1 = v0; i1 = i0; v0 = v; i0 = i;
  } else if (v > v1 || (v == v1 && i < i1)) {
    v2 = v1; i2 = i1; v1 = v; i1 = i;
  } else if (v > v2 || (v == v2 && i < i2)) {
    v2 = v; i2 = i;
  }
}

// merge 16 chunks' candidates of batch b -> indices sorted ascending
__device__ __forceinline__ void merge_top3(
    const float* __restrict__ candv, const int* __restrict__ candi,
    int b, int& a, int& bb, int& c)
{
  float v0 = -3.4e38f, v1 = -3.4e38f, v2 = -3.4e38f;
  int i0 = 0x7fffffff, i1 = 0x7fffffff, i2 = 0x7fffffff;
  const int base = b * 48;
#pragma unroll
  for (int k = 0; k < 48; ++k)
    ins3(candv[base + k], candi[base + k], v0, i0, v1, i1, v2, i2);
  a = i0; bb = i1; c = i2;
  int tw;
  if (a > bb) { tw = a; a = bb; bb = tw; }
  if (bb > c) { tw = bb; bb = c; c = tw; }
  if (a > bb) { tw = a; a = bb; bb = tw; }
}

// ---------------------------------------------------------------------------
// Gates GEMM: P[sp][64][4096] = [x|h] @ [W_ih|W_hh]^T, split-K.
// Grid (32 nb, 8 sp) x 512 thr.  For t>0, x rows are gathered from enc via a
// per-thread self-merge of the previous step's top3 candidates (no extra
// launch, no fence -- stream order makes candv/candi visible).  Block (0,0)
// additionally writes the previous step's idx output.
// ---------------------------------------------------------------------------
__global__ __launch_bounds__(512, 2) void gemm_gates(
    const float* __restrict__ x0, const float* __restrict__ h_prev,
    const float* __restrict__ W_ih, const float* __restrict__ W_hh,
    const float* __restrict__ enc,
    const float* __restrict__ candv, const int* __restrict__ candi, int gather,
    float* __restrict__ P, float* __restrict__ idx_out_prev)
{
  __shared__ float As[16 * 68];
  __shared__ float Bs[16 * 132];
  const int tid = threadIdx.x;
  const int nb = blockIdx.x, sp = blockIdx.y;
  const int ks = sp * 512;

  const float* A; const float* W; int ldA, ldW, koff; int seg0;
  if (ks < 3072) { A = x0; W = W_ih; ldA = 3072; ldW = 3072; koff = ks; seg0 = 1; }
  else { A = h_prev; W = W_hh; ldA = 1024; ldW = 1024; koff = ks - 3072; seg0 = 0; }

  const int tn = tid & 31, tm = tid >> 5;
  const int lr = tid >> 2, lc = (tid & 3) * 4;

  // previous-step idx output (one designated block; cheap, runs before k-loop)
  if (gather && nb == 0 && sp == 0 && tid < 64) {
    int a, bb, c;
    merge_top3(candv, candi, tid, a, bb, c);
    float* io = idx_out_prev + tid * 3;
    io[0] = (float)a; io[1] = (float)bb; io[2] = (float)c;
  }

  float acc[4][4];
#pragma unroll
  for (int i = 0; i < 4; ++i)
#pragma unroll
    for (int j = 0; j < 4; ++j) acc[i][j] = 0.f;

  const float* Wrow = W + (size_t)(nb * 128 + lr) * ldW + koff + lc;
  const float* Arow = nullptr;
  if (tid < 256) {
    if (seg0 && gather) {
      int a, bb, c;
      merge_top3(candv, candi, lr, a, bb, c);
      const int g = koff >> 10;
      const int ei = (g == 0) ? a : ((g == 1) ? bb : c);
      Arow = enc + ((size_t)lr * 512 + ei) * 1024 + (koff & 1023) + lc;
    } else {
      Arow = A + (size_t)lr * ldA + koff + lc;
    }
  }

  for (int k0 = 0; k0 < 512; k0 += 16) {
    float4 b4 = *(const float4*)(Wrow + k0);
    if (tid < 256) {
      float4 a4 = *(const float4*)(Arow + k0);
      As[(lc + 0) * 68 + lr] = a4.x; As[(lc + 1) * 68 + lr] = a4.y;
      As[(lc + 2) * 68 + lr] = a4.z; As[(lc + 3) * 68 + lr] = a4.w;
    }
    Bs[(lc + 0) * 132 + lr] = b4.x; Bs[(lc + 1) * 132 + lr] = b4.y;
    Bs[(lc + 2) * 132 + lr] = b4.z; Bs[(lc + 3) * 132 + lr] = b4.w;
    __syncthreads();
#pragma unroll
    for (int k = 0; k < 16; ++k) {
      float av[4], bv[4];
      *(float4*)av = *(const float4*)(As + k * 68 + tm * 4);
      *(float4*)bv = *(const float4*)(Bs + k * 132 + tn * 4);
#pragma unroll
      for (int i = 0; i < 4; ++i)
#pragma unroll
        for (int j = 0; j < 4; ++j)
          acc[i][j] = fmaf(av[i], bv[j], acc[i][j]);
    }
    __syncthreads();
  }
  float* Pb = P + (size_t)sp * 64 * 4096 + nb * 128;
#pragma unroll
  for (int i = 0; i < 4; ++i)
    *(float4*)(Pb + (size_t)(tm * 4 + i) * 4096 + tn * 4) =
        make_float4(acc[i][0], acc[i][1], acc[i][2], acc[i][3]);
}

// ---------------------------------------------------------------------------
// Split-K GEMM (no gather): P[sp][64][N] = A[64,Kslice] @ W[N,Kslice]^T
// ---------------------------------------------------------------------------
__global__ __launch_bounds__(512, 2) void gemm5(
    const float* __restrict__ A0, int ldA0, const float* __restrict__ W0, int ldW0,
    int K0,
    const float* __restrict__ A1, int ldA1, const float* __restrict__ W1, int ldW1,
    float* __restrict__ P, int N, int KS)
{
  __shared__ float As[16 * 68];
  __shared__ float Bs[16 * 132];
  const int tid = threadIdx.x;
  const int nb = blockIdx.x, sp = blockIdx.y;
  const int ks = sp * KS;

  const float* A; const float* W; int ldA, ldW, koff;
  if (ks < K0) { A = A0; W = W0; ldA = ldA0; ldW = ldW0; koff = ks; }
  else { A = A1; W = W1; ldA = ldA1; ldW = ldW1; koff = ks - K0; }

  const int tn = tid & 31, tm = tid >> 5;
  const int lr = tid >> 2, lc = (tid & 3) * 4;

  float acc[4][4];
#pragma unroll
  for (int i = 0; i < 4; ++i)
#pragma unroll
    for (int j = 0; j < 4; ++j) acc[i][j] = 0.f;

  const float* Wrow = W + (size_t)(nb * 128 + lr) * ldW + koff + lc;
  const float* Arow = (tid < 256) ? A + (size_t)lr * ldA + koff + lc : nullptr;

  for (int k0 = 0; k0 < KS; k0 += 16) {
    float4 b4 = *(const float4*)(Wrow + k0);
    if (tid < 256) {
      float4 a4 = *(const float4*)(Arow + k0);
      As[(lc + 0) * 68 + lr] = a4.x; As[(lc + 1) * 68 + lr] = a4.y;
      As[(lc + 2) * 68 + lr] = a4.z; As[(lc + 3) * 68 + lr] = a4.w;
    }
    Bs[(lc + 0) * 132 + lr] = b4.x; Bs[(lc + 1) * 132 + lr] = b4.y;
    Bs[(lc + 2) * 132 + lr] = b4.z; Bs[(lc + 3) * 132 + lr] = b4.w;
    __syncthreads();
#pragma unroll
    for (int k = 0; k < 16; ++k) {
      float av[4], bv[4];
      *(float4*)av = *(const float4*)(As + k * 68 + tm * 4);
      *(float4*)bv = *(const float4*)(Bs + k * 132 + tn * 4);
#pragma unroll
      for (int i = 0; i < 4; ++i)
#pragma unroll
        for (int j = 0; j < 4; ++j)
          acc[i][j] = fmaf(av[i], bv[j], acc[i][j]);
    }
    __syncthreads();
  }
  float* Pb = P + (size_t)sp * 64 * N + nb * 128;
#pragma unroll
  for (int i = 0; i < 4; ++i)
    *(float4*)(Pb + (size_t)(tm * 4 + i) * N + tn * 4) =
        make_float4(acc[i][0], acc[i][1], acc[i][2], acc[i][3]);
}

// ---------------------------------------------------------------------------
// LSTM: reduce 8 gate partials + biases, pointwise -> h', c'.  float4 wide.
// ---------------------------------------------------------------------------
__global__ __launch_bounds__(256) void lstm_red(
    const float* __restrict__ P, const float* __restrict__ b_ih,
    const float* __restrict__ b_hh, const float* __restrict__ c_in,
    float* __restrict__ h_out, float* __restrict__ c_out)
{
  int idx = blockIdx.x * 256 + threadIdx.x;   // 0..16383
  int b = idx >> 8, j4 = (idx & 255) * 4;
  float g[4][4];
#pragma unroll
  for (int c = 0; c < 4; ++c) {
    int n = c * 1024 + j4;
    float4 s = *(const float4*)(b_ih + n);
    float4 s2 = *(const float4*)(b_hh + n);
    s.x += s2.x; s.y += s2.y; s.z += s2.z; s.w += s2.w;
#pragma unroll
    for (int sp = 0; sp < 8; ++sp) {
      float4 v = *(const float4*)(P + ((size_t)sp * 64 + b) * 4096 + n);
      s.x += v.x; s.y += v.y; s.z += v.z; s.w += v.w;
    }
    g[c][0] = s.x; g[c][1] = s.y; g[c][2] = s.z; g[c][3] = s.w;
  }
  float4 cp = *(const float4*)(c_in + b * 1024 + j4);
  float cv[4] = {cp.x, cp.y, cp.z, cp.w};
  float4 ho, co;
  float* hp = &ho.x; float* cpn = &co.x;
#pragma unroll
  for (int e = 0; e < 4; ++e) {
    float c = sigm(g[1][e]) * cv[e] + sigm(g[0][e]) * tanhf(g[2][e]);
    cpn[e] = c;
    hp[e] = sigm(g[3][e]) * tanhf(c);
  }
  *(float4*)(c_out + b * 1024 + j4) = co;
  *(float4*)(h_out + b * 1024 + j4) = ho;
}

// ---------------------------------------------------------------------------
// Attention with fused qkv-partial reduce. 512 blocks (b,h) x 128 threads.
// ---------------------------------------------------------------------------
__global__ __launch_bounds__(128) void attn_fused(
    const float* __restrict__ P, const float* __restrict__ bqkv,
    float* __restrict__ Kc, float* __restrict__ Vc,
    float* __restrict__ ctx, int t)
{
  const float scale = 0.08838834764831845f;  // 1/sqrt(128)
  int bh = blockIdx.x;
  int b = bh >> 3, h = bh & 7;
  int d = threadIdx.x;
  __shared__ float qs[128];
  __shared__ float sc[S_];

  const float* Pb = P + (size_t)b * 3072 + h * 128 + d;
  float qv = bqkv[h * 128 + d];
  float kv = bqkv[1024 + h * 128 + d];
  float vv = bqkv[2048 + h * 128 + d];
#pragma unroll
  for (int sp = 0; sp < 8; ++sp) {
    const float* pp = Pb + (size_t)sp * 64 * 3072;
    qv += pp[0]; kv += pp[1024]; vv += pp[2048];
  }
  float* Kb = Kc + (size_t)(b * NH_ + h) * S_ * HD_;
  float* Vb = Vc + (size_t)(b * NH_ + h) * S_ * HD_;
  Kb[t * 128 + d] = kv;
  Vb[t * 128 + d] = vv;
  qs[d] = qv;
  __syncthreads();

  int wave = d >> 6, lane = d & 63;
  for (int s = wave; s <= t; s += 2) {
    float pr = qs[lane] * Kb[s * 128 + lane] + qs[lane + 64] * Kb[s * 128 + lane + 64];
#pragma unroll
    for (int off = 32; off > 0; off >>= 1) pr += __shfl_down(pr, off, 64);
    if (lane == 0) sc[s] = pr * scale;
  }
  __syncthreads();

  float m = -3.4e38f;
  for (int s = 0; s <= t; ++s) m = fmaxf(m, sc[s]);
  float den = 0.f;
  for (int s = 0; s <= t; ++s) den += expf(sc[s] - m);
  float acc = 0.f;
  for (int s = 0; s <= t; ++s) acc += expf(sc[s] - m) * Vb[s * 128 + d];
  ctx[(size_t)b * 1024 + h * 128 + d] = acc / den;
}

// ---------------------------------------------------------------------------
// logits4: fused qt-reduce + wide logits + per-block top3.
// 1024 blocks (b, 32-row chunk) x 256 thr (4 waves x 8 rows).  2-row-paired
// inner loop: 8 float4 loads in flight / wave, two independent FMA chains,
// interleaved butterflies.  Per-block top3 -> candv/candi[b*16+ng].
// ---------------------------------------------------------------------------
__global__ __launch_bounds__(256) void logits4(
    const float* __restrict__ P, const float* __restrict__ bc,
    const float* __restrict__ enc, float* __restrict__ out,
    float* __restrict__ candv, int* __restrict__ candi)
{
  __shared__ float qs[1024];
  __shared__ float cv[12];
  __shared__ int   ci[12];
  const int tid = threadIdx.x;
  const int b = blockIdx.x >> 4, ng = blockIdx.x & 15;

  // stage q[b][0..1023] with fused split-K reduce (+bc)
  {
    const int j4 = tid * 4;
    float4 s = *(const float4*)(bc + j4);
#pragma unroll
    for (int sp = 0; sp < 16; ++sp) {
      float4 v = *(const float4*)(P + ((size_t)sp * 64 + b) * 1024 + j4);
      s.x += v.x; s.y += v.y; s.z += v.z; s.w += v.w;
    }
    *(float4*)(qs + j4) = s;
  }
  __syncthreads();

  const int wave = tid >> 6, lane = tid & 63;
  float4 q0 = *(const float4*)(qs + lane * 4);
  float4 q1 = *(const float4*)(qs + 256 + lane * 4);
  float4 q2 = *(const float4*)(qs + 512 + lane * 4);
  float4 q3 = *(const float4*)(qs + 768 + lane * 4);

  const int row0 = ng * 32 + wave * 8;            // 8 rows per wave
  const float* eb = enc + ((size_t)b * N_ + row0) * 1024 + lane * 4;
  float* lo = out + (size_t)b * N_ + row0;
  float v0 = -3.4e38f, v1 = -3.4e38f, v2 = -3.4e38f;
  int i0 = 0x7fffffff, i1 = 0x7fffffff, i2 = 0x7fffffff;
  float myout = 0.f;
#pragma unroll
  for (int r = 0; r < 8; r += 2) {
    const float* ea = eb + (size_t)r * 1024;
    const float* eb2 = eb + (size_t)(r + 1) * 1024;
    float4 a0 = *(const float4*)(ea);
    float4 a1 = *(const float4*)(ea + 256);
    float4 a2 = *(const float4*)(ea + 512);
    float4 a3 = *(const float4*)(ea + 768);
    float4 b0 = *(const float4*)(eb2);
    float4 b1 = *(const float4*)(eb2 + 256);
    float4 b2 = *(const float4*)(eb2 + 512);
    float4 b3 = *(const float4*)(eb2 + 768);
    float s0 = 0.f, s1 = 0.f;
    s0 = fmaf(q0.x, a0.x, s0); s1 = fmaf(q0.x, b0.x, s1);
    s0 = fmaf(q0.y, a0.y, s0); s1 = fmaf(q0.y, b0.y, s1);
    s0 = fmaf(q0.z, a0.z, s0); s1 = fmaf(q0.z, b0.z, s1);
    s0 = fmaf(q0.w, a0.w, s0); s1 = fmaf(q0.w, b0.w, s1);
    s0 = fmaf(q1.x, a1.x, s0); s1 = fmaf(q1.x, b1.x, s1);
    s0 = fmaf(q1.y, a1.y, s0); s1 = fmaf(q1.y, b1.y, s1);
    s0 = fmaf(q1.z, a1.z, s0); s1 = fmaf(q1.z, b1.z, s1);
    s0 = fmaf(q1.w, a1.w, s0); s1 = fmaf(q1.w, b1.w, s1);
    s0 = fmaf(q2.x, a2.x, s0); s1 = fmaf(q2.x, b2.x, s1);
    s0 = fmaf(q2.y, a2.y, s0); s1 = fmaf(q2.y, b2.y, s1);
    s0 = fmaf(q2.z, a2.z, s0); s1 = fmaf(q2.z, b2.z, s1);
    s0 = fmaf(q2.w, a2.w, s0); s1 = fmaf(q2.w, b2.w, s1);
    s0 = fmaf(q3.x, a3.x, s0); s1 = fmaf(q3.x, b3.x, s1);
    s0 = fmaf(q3.y, a3.y, s0); s1 = fmaf(q3.y, b3.y, s1);
    s0 = fmaf(q3.z, a3.z, s0); s1 = fmaf(q3.z, b3.z, s1);
    s0 = fmaf(q3.w, a3.w, s0); s1 = fmaf(q3.w, b3.w, s1);
#pragma unroll
    for (int off = 32; off > 0; off >>= 1) {
      s0 += __shfl_xor(s0, off, 64);
      s1 += __shfl_xor(s1, off, 64);
    }
    if (lane == r) myout = s0;
    if (lane == r + 1) myout = s1;
    ins3(s0, row0 + r, v0, i0, v1, i1, v2, i2);
    ins3(s1, row0 + r + 1, v0, i0, v1, i1, v2, i2);
  }
  if (lane < 8) lo[lane] = myout;
  if (lane == 0) {
    cv[wave * 3 + 0] = v0; ci[wave * 3 + 0] = i0;
    cv[wave * 3 + 1] = v1; ci[wave * 3 + 1] = i1;
    cv[wave * 3 + 2] = v2; ci[wave * 3 + 2] = i2;
  }
  __syncthreads();
  if (tid == 0) {
    float w0 = -3.4e38f, w1 = -3.4e38f, w2 = -3.4e38f;
    int j0 = 0x7fffffff, j1 = 0x7fffffff, j2 = 0x7fffffff;
#pragma unroll
    for (int k = 0; k < 12; ++k)
      ins3(cv[k], ci[k], w0, j0, w1, j1, w2, j2);
    candv[blockIdx.x * 3 + 0] = w0; candi[blockIdx.x * 3 + 0] = j0;
    candv[blockIdx.x * 3 + 1] = w1; candi[blockIdx.x * 3 + 1] = j1;
    candv[blockIdx.x * 3 + 2] = w2; candi[blockIdx.x * 3 + 2] = j2;
  }
}

// ---------------------------------------------------------------------------
// Final merge for the last step only (steps 0..22 are merged inside the next
// step's gates kernel).  1 block x 64 threads.
// ---------------------------------------------------------------------------
__global__ __launch_bounds__(64) void top3_final(
    const float* __restrict__ candv, const int* __restrict__ candi,
    float* __restrict__ idx_out)
{
  int b = threadIdx.x;
  int a, bb, c;
  merge_top3(candv, candi, b, a, bb, c);
  idx_out[b * 3 + 0] = (float)a;
  idx_out[b * 3 + 1] = (float)bb;
  idx_out[b * 3 + 2] = (float)c;
}

// ---------------------------------------------------------------------------
extern "C" void kernel_launch(void* const* d_in, const int* in_sizes, int n_in,
                              void* d_out, int out_size, void* d_ws, size_t ws_size,
                              hipStream_t stream)
{
  (void)in_sizes; (void)n_in; (void)out_size; (void)ws_size;
  const float* enc   = (const float*)d_in[0];
  const float* h0    = (const float*)d_in[1];
  const float* c0    = (const float*)d_in[2];
  const float* x0    = (const float*)d_in[4];
  const float* W_ih  = (const float*)d_in[6];
  const float* b_ih  = (const float*)d_in[7];
  const float* W_hh  = (const float*)d_in[8];
  const float* b_hh  = (const float*)d_in[9];
  const float* Wqkv  = (const float*)d_in[10];
  const float* bqkv  = (const float*)d_in[11];
  const float* Wout  = (const float*)d_in[12];
  const float* bout  = (const float*)d_in[13];
  const float* Wqt   = (const float*)d_in[14];
  const float* bqt   = (const float*)d_in[15];

  float* ws    = (float*)d_ws;
  float* P     = ws;                          // 8*64*4096 floats
  float* W2    = P + 8 * 64 * 4096;           // 1024*2048
  float* bc    = W2 + 1024 * 2048;            // 1024
  float* hbuf  = bc + 1024;                   // 64*1024
  float* cbuf  = hbuf + 64 * 1024;            // 64*1024
  float* ctx   = cbuf + 64 * 1024;            // 64*1024
  float* Kc    = ctx + 64 * 1024;             // 64*8*24*128
  float* Vc    = Kc + 64 * NH_ * S_ * HD_;
  float* candv = Vc + 64 * NH_ * S_ * HD_;    // 1024*3
  int*   candi = (int*)(candv + 1024 * 3);    // 1024*3

  float* logits_out = (float*)d_out;                     // [S,B,N]
  float* idx_out    = logits_out + (size_t)S_ * B_ * N_; // [S,B,3] as float

  // once per launch: combined qt weights/bias
  wc_pre<<<dim3(256), dim3(256), 0, stream>>>(Wqt, Wout, bout, bqt, W2, bc);

  for (int t = 0; t < S_; ++t) {
    const float* hprev = (t == 0) ? h0 : hbuf;
    const float* cprev = (t == 0) ? c0 : cbuf;

    // gates = [x|h] @ [W_ih|W_hh]^T -> P[8][64][4096]
    // (for t>0: x gathered from enc via self-merged top3; block (0,0) also
    //  writes idx output of step t-1)
    gemm_gates<<<dim3(32, 8), dim3(512), 0, stream>>>(
        x0, hprev, W_ih, W_hh, enc, candv, candi, t > 0, P,
        (t > 0) ? idx_out + (size_t)(t - 1) * B_ * 3 : nullptr);
    lstm_red<<<dim3(64), dim3(256), 0, stream>>>(P, b_ih, b_hh, cprev, hbuf, cbuf);

    // qkv = h @ Wqkv^T -> P[8][64][3072]
    gemm5<<<dim3(24, 8), dim3(512), 0, stream>>>(
        hbuf, 1024, Wqkv, 1024, 1024,
        hbuf, 1024, Wqkv, 1024,
        P, 3072, 128);
    attn_fused<<<dim3(512), dim3(128), 0, stream>>>(P, bqkv, Kc, Vc, ctx, t);

    // query = [h|ctx] @ W2^T (+bc at reduce) -> P[16][64][1024]
    gemm5<<<dim3(8, 16), dim3(512), 0, stream>>>(
        hbuf, 1024, W2, 2048, 1024,
        ctx, 1024, W2 + 1024, 2048,
        P, 1024, 128);

    // logits + per-chunk top3
    logits4<<<dim3(1024), dim3(256), 0, stream>>>(
        P, bc, enc, logits_out + (size_t)t * B_ * N_, candv, candi);
  }
  // last step's idx output
  top3_final<<<dim3(1), dim3(64), 0, stream>>>(
      candv, candi, idx_out + (size_t)(S_ - 1) * B_ * 3);
}

// Round 6
// 3801.886 us; speedup vs baseline: 1.7799x; 1.3477x over previous
//
#include <hip/hip_runtime.h>
#include <math.h>

#define B_  64
#define N_  512
#define H_  1024
#define NH_ 8
#define HD_ 128
#define S_  24

// ---------------------------------------------------------------------------
// Precompute (once per launch, fused):
//   W2[n][0..1023] = 0.5*Wqt[n][k];  W2[n][1024+k] = 0.5*(Wqt·Wout)[n][k]
//   bc[n] = 0.5*dot(Wqt[n,:], bout) + bqt[n]
// 256 blocks x 256 threads: 16x16 grid of 64x64 tiles.
// ---------------------------------------------------------------------------
__global__ __launch_bounds__(256) void wc_pre(
    const float* __restrict__ Wqt, const float* __restrict__ Wout,
    const float* __restrict__ bout, const float* __restrict__ bqt,
    float* __restrict__ W2, float* __restrict__ bc)
{
  __shared__ float As[16][68];   // [m][n] of Wqt tile (transposed stage)
  __shared__ float Bs[16][68];   // [m][k] of Wout tile
  const int tid = threadIdx.x;
  const int k0 = (blockIdx.x & 15) * 64;
  const int n0 = (blockIdx.x >> 4) * 64;
  const int tn = tid & 15, tm = tid >> 4;

  // copy half: W2[n][k] = 0.5*Wqt[n][k]
#pragma unroll
  for (int i = 0; i < 4; ++i) {
    int n = n0 + tm * 4 + i;
    float4 w = *(const float4*)(Wqt + (size_t)n * 1024 + k0 + tn * 4);
    *(float4*)(W2 + (size_t)n * 2048 + k0 + tn * 4) =
        make_float4(0.5f * w.x, 0.5f * w.y, 0.5f * w.z, 0.5f * w.w);
  }

  float acc[4][4];
#pragma unroll
  for (int i = 0; i < 4; ++i)
#pragma unroll
    for (int j = 0; j < 4; ++j) acc[i][j] = 0.f;

  for (int m0 = 0; m0 < 1024; m0 += 16) {
    {
      int nn = tid >> 2, mm = (tid & 3) * 4;
      float4 a = *(const float4*)(Wqt + (size_t)(n0 + nn) * 1024 + m0 + mm);
      As[mm + 0][nn] = a.x; As[mm + 1][nn] = a.y;
      As[mm + 2][nn] = a.z; As[mm + 3][nn] = a.w;
      int mr = tid >> 4, kc = (tid & 15) * 4;
      float4 b = *(const float4*)(Wout + (size_t)(m0 + mr) * 1024 + k0 + kc);
      *(float4*)(&Bs[mr][kc]) = b;
    }
    __syncthreads();
#pragma unroll
    for (int m = 0; m < 16; ++m) {
      float av[4], bv[4];
      *(float4*)av = *(const float4*)(&As[m][tm * 4]);
      *(float4*)bv = *(const float4*)(&Bs[m][tn * 4]);
#pragma unroll
      for (int i = 0; i < 4; ++i)
#pragma unroll
        for (int j = 0; j < 4; ++j)
          acc[i][j] = fmaf(av[i], bv[j], acc[i][j]);
    }
    __syncthreads();
  }
#pragma unroll
  for (int i = 0; i < 4; ++i) {
    int n = n0 + tm * 4 + i;
    *(float4*)(W2 + (size_t)n * 2048 + 1024 + k0 + tn * 4) =
        make_float4(0.5f * acc[i][0], 0.5f * acc[i][1],
                    0.5f * acc[i][2], 0.5f * acc[i][3]);
  }

  // bc part (independent; wave per n, 4 n per block)
  {
    int w = tid >> 6, lane = tid & 63;
    int n = blockIdx.x * 4 + w;
    const float* row = Wqt + (size_t)n * 1024;
    float s = 0.f;
#pragma unroll
    for (int c = 0; c < 4; ++c) {
      float4 a = *(const float4*)(row + lane * 16 + c * 4);
      float4 b = *(const float4*)(bout + lane * 16 + c * 4);
      s = fmaf(a.x, b.x, fmaf(a.y, b.y, fmaf(a.z, b.z, fmaf(a.w, b.w, s))));
    }
#pragma unroll
    for (int off = 32; off > 0; off >>= 1) s += __shfl_down(s, off, 64);
    if (lane == 0) bc[n] = 0.5f * s + bqt[n];
  }
}

__device__ __forceinline__ float sigm(float x) { return 1.f / (1.f + expf(-x)); }

__device__ __forceinline__ void ins3(float v, int i,
    float& v0, int& i0, float& v1, int& i1, float& v2, int& i2)
{
  if (v > v0 || (v == v0 && i < i0)) {
    v2 = v1; i2 = i1; v1 = v0; i1 = i0; v0 = v; i0 = i;
  } else if (v > v1 || (v == v1 && i < i1)) {
    v2 = v1; i2 = i1; v1 = v; i1 = i;
  } else if (v > v2 || (v == v2 && i < i2)) {
    v2 = v; i2 = i;
  }
}

// ---------------------------------------------------------------------------
// Split-K GEMM: P[sp][64][N] = A[64,K-slice] @ W[N,K-slice]^T
// Two K-segments with independent (A, ldA, W, ldW); koff = ks or ks-K0.
// Tile 64m x 128n, 512 threads, KS per split. Optional seg0 A-gather:
// A row b = enc[b*512 + idxi[b*3 + (koff>>10)]] (x = top3-gathered enc rows).
// ---------------------------------------------------------------------------
__global__ __launch_bounds__(512, 2) void gemm5(
    const float* __restrict__ A0, int ldA0, const float* __restrict__ W0, int ldW0,
    int K0,
    const float* __restrict__ A1, int ldA1, const float* __restrict__ W1, int ldW1,
    const float* __restrict__ enc, const int* __restrict__ idxi, int gather,
    float* __restrict__ P, int N, int KS)
{
  __shared__ float As[16 * 68];
  __shared__ float Bs[16 * 132];
  const int tid = threadIdx.x;
  const int nb = blockIdx.x, sp = blockIdx.y;
  const int ks = sp * KS;

  const float* A; const float* W; int ldA, ldW, koff; int seg0;
  if (ks < K0) { A = A0; W = W0; ldA = ldA0; ldW = ldW0; koff = ks; seg0 = 1; }
  else { A = A1; W = W1; ldA = ldA1; ldW = ldW1; koff = ks - K0; seg0 = 0; }

  const int tn = tid & 31, tm = tid >> 5;
  const int lr = tid >> 2, lc = (tid & 3) * 4;

  float acc[4][4];
#pragma unroll
  for (int i = 0; i < 4; ++i)
#pragma unroll
    for (int j = 0; j < 4; ++j) acc[i][j] = 0.f;

  const float* Wrow = W + (size_t)(nb * 128 + lr) * ldW + koff + lc;
  const float* Arow = nullptr;
  if (tid < 256) {
    if (seg0 && gather) {
      int ei = idxi[lr * 3 + (koff >> 10)];
      Arow = enc + ((size_t)lr * 512 + ei) * 1024 + (koff & 1023) + lc;
    } else {
      Arow = A + (size_t)lr * ldA + koff + lc;
    }
  }

  for (int k0 = 0; k0 < KS; k0 += 16) {
    float4 b4 = *(const float4*)(Wrow + k0);
    if (tid < 256) {
      float4 a4 = *(const float4*)(Arow + k0);
      As[(lc + 0) * 68 + lr] = a4.x; As[(lc + 1) * 68 + lr] = a4.y;
      As[(lc + 2) * 68 + lr] = a4.z; As[(lc + 3) * 68 + lr] = a4.w;
    }
    Bs[(lc + 0) * 132 + lr] = b4.x; Bs[(lc + 1) * 132 + lr] = b4.y;
    Bs[(lc + 2) * 132 + lr] = b4.z; Bs[(lc + 3) * 132 + lr] = b4.w;
    __syncthreads();
#pragma unroll
    for (int k = 0; k < 16; ++k) {
      float av[4], bv[4];
      *(float4*)av = *(const float4*)(As + k * 68 + tm * 4);
      *(float4*)bv = *(const float4*)(Bs + k * 132 + tn * 4);
#pragma unroll
      for (int i = 0; i < 4; ++i)
#pragma unroll
        for (int j = 0; j < 4; ++j)
          acc[i][j] = fmaf(av[i], bv[j], acc[i][j]);
    }
    __syncthreads();
  }
  float* Pb = P + (size_t)sp * 64 * N + nb * 128;
#pragma unroll
  for (int i = 0; i < 4; ++i)
    *(float4*)(Pb + (size_t)(tm * 4 + i) * N + tn * 4) =
        make_float4(acc[i][0], acc[i][1], acc[i][2], acc[i][3]);
}

// ---------------------------------------------------------------------------
// LSTM: reduce 8 gate partials + biases, pointwise -> h', c'.  float4 wide.
// ---------------------------------------------------------------------------
__global__ __launch_bounds__(256) void lstm_red(
    const float* __restrict__ P, const float* __restrict__ b_ih,
    const float* __restrict__ b_hh, const float* __restrict__ c_in,
    float* __restrict__ h_out, float* __restrict__ c_out)
{
  int idx = blockIdx.x * 256 + threadIdx.x;   // 0..16383
  int b = idx >> 8, j4 = (idx & 255) * 4;
  float g[4][4];
#pragma unroll
  for (int c = 0; c < 4; ++c) {
    int n = c * 1024 + j4;
    float4 s = *(const float4*)(b_ih + n);
    float4 s2 = *(const float4*)(b_hh + n);
    s.x += s2.x; s.y += s2.y; s.z += s2.z; s.w += s2.w;
#pragma unroll
    for (int sp = 0; sp < 8; ++sp) {
      float4 v = *(const float4*)(P + ((size_t)sp * 64 + b) * 4096 + n);
      s.x += v.x; s.y += v.y; s.z += v.z; s.w += v.w;
    }
    g[c][0] = s.x; g[c][1] = s.y; g[c][2] = s.z; g[c][3] = s.w;
  }
  float4 cp = *(const float4*)(c_in + b * 1024 + j4);
  float cv[4] = {cp.x, cp.y, cp.z, cp.w};
  float4 ho, co;
  float* hp = &ho.x; float* cpn = &co.x;
#pragma unroll
  for (int e = 0; e < 4; ++e) {
    float c = sigm(g[1][e]) * cv[e] + sigm(g[0][e]) * tanhf(g[2][e]);
    cpn[e] = c;
    hp[e] = sigm(g[3][e]) * tanhf(c);
  }
  *(float4*)(c_out + b * 1024 + j4) = co;
  *(float4*)(h_out + b * 1024 + j4) = ho;
}

// ---------------------------------------------------------------------------
// Attention with fused qkv-partial reduce. 512 blocks (b,h) x 128 threads.
// ---------------------------------------------------------------------------
__global__ __launch_bounds__(128) void attn_fused(
    const float* __restrict__ P, const float* __restrict__ bqkv,
    float* __restrict__ Kc, float* __restrict__ Vc,
    float* __restrict__ ctx, int t)
{
  const float scale = 0.08838834764831845f;  // 1/sqrt(128)
  int bh = blockIdx.x;
  int b = bh >> 3, h = bh & 7;
  int d = threadIdx.x;
  __shared__ float qs[128];
  __shared__ float sc[S_];

  const float* Pb = P + (size_t)b * 3072 + h * 128 + d;
  float qv = bqkv[h * 128 + d];
  float kv = bqkv[1024 + h * 128 + d];
  float vv = bqkv[2048 + h * 128 + d];
#pragma unroll
  for (int sp = 0; sp < 8; ++sp) {
    const float* pp = Pb + (size_t)sp * 64 * 3072;
    qv += pp[0]; kv += pp[1024]; vv += pp[2048];
  }
  float* Kb = Kc + (size_t)(b * NH_ + h) * S_ * HD_;
  float* Vb = Vc + (size_t)(b * NH_ + h) * S_ * HD_;
  Kb[t * 128 + d] = kv;
  Vb[t * 128 + d] = vv;
  qs[d] = qv;
  __syncthreads();

  int wave = d >> 6, lane = d & 63;
  for (int s = wave; s <= t; s += 2) {
    float pr = qs[lane] * Kb[s * 128 + lane] + qs[lane + 64] * Kb[s * 128 + lane + 64];
#pragma unroll
    for (int off = 32; off > 0; off >>= 1) pr += __shfl_down(pr, off, 64);
    if (lane == 0) sc[s] = pr * scale;
  }
  __syncthreads();

  float m = -3.4e38f;
  for (int s = 0; s <= t; ++s) m = fmaxf(m, sc[s]);
  float den = 0.f;
  for (int s = 0; s <= t; ++s) den += expf(sc[s] - m);
  float acc = 0.f;
  for (int s = 0; s <= t; ++s) acc += expf(sc[s] - m) * Vb[s * 128 + d];
  ctx[(size_t)b * 1024 + h * 128 + d] = acc / den;
}

// ---------------------------------------------------------------------------
// logits4: fused qt-reduce + wide logits + per-block top3.
// 1024 blocks (b, 32-row chunk) x 256 thr (4 waves x 8 rows).  2-row-paired
// inner loop: 8 float4 loads in flight / wave, two independent FMA chains,
// interleaved butterflies.  Per-block top3 -> candv/candi[b*16+ng].
// ---------------------------------------------------------------------------
__global__ __launch_bounds__(256) void logits4(
    const float* __restrict__ P, const float* __restrict__ bc,
    const float* __restrict__ enc, float* __restrict__ out,
    float* __restrict__ candv, int* __restrict__ candi)
{
  __shared__ float qs[1024];
  __shared__ float cv[12];
  __shared__ int   ci[12];
  const int tid = threadIdx.x;
  const int b = blockIdx.x >> 4, ng = blockIdx.x & 15;

  // stage q[b][0..1023] with fused split-K reduce (+bc)
  {
    const int j4 = tid * 4;
    float4 s = *(const float4*)(bc + j4);
#pragma unroll
    for (int sp = 0; sp < 16; ++sp) {
      float4 v = *(const float4*)(P + ((size_t)sp * 64 + b) * 1024 + j4);
      s.x += v.x; s.y += v.y; s.z += v.z; s.w += v.w;
    }
    *(float4*)(qs + j4) = s;
  }
  __syncthreads();

  const int wave = tid >> 6, lane = tid & 63;
  float4 q0 = *(const float4*)(qs + lane * 4);
  float4 q1 = *(const float4*)(qs + 256 + lane * 4);
  float4 q2 = *(const float4*)(qs + 512 + lane * 4);
  float4 q3 = *(const float4*)(qs + 768 + lane * 4);

  const int row0 = ng * 32 + wave * 8;            // 8 rows per wave
  const float* eb = enc + ((size_t)b * N_ + row0) * 1024 + lane * 4;
  float* lo = out + (size_t)b * N_ + row0;
  float v0 = -3.4e38f, v1 = -3.4e38f, v2 = -3.4e38f;
  int i0 = 0x7fffffff, i1 = 0x7fffffff, i2 = 0x7fffffff;
  float myout = 0.f;
#pragma unroll
  for (int r = 0; r < 8; r += 2) {
    const float* ea = eb + (size_t)r * 1024;
    const float* eb2 = eb + (size_t)(r + 1) * 1024;
    float4 a0 = *(const float4*)(ea);
    float4 a1 = *(const float4*)(ea + 256);
    float4 a2 = *(const float4*)(ea + 512);
    float4 a3 = *(const float4*)(ea + 768);
    float4 b0 = *(const float4*)(eb2);
    float4 b1 = *(const float4*)(eb2 + 256);
    float4 b2 = *(const float4*)(eb2 + 512);
    float4 b3 = *(const float4*)(eb2 + 768);
    float s0 = 0.f, s1 = 0.f;
    s0 = fmaf(q0.x, a0.x, s0); s1 = fmaf(q0.x, b0.x, s1);
    s0 = fmaf(q0.y, a0.y, s0); s1 = fmaf(q0.y, b0.y, s1);
    s0 = fmaf(q0.z, a0.z, s0); s1 = fmaf(q0.z, b0.z, s1);
    s0 = fmaf(q0.w, a0.w, s0); s1 = fmaf(q0.w, b0.w, s1);
    s0 = fmaf(q1.x, a1.x, s0); s1 = fmaf(q1.x, b1.x, s1);
    s0 = fmaf(q1.y, a1.y, s0); s1 = fmaf(q1.y, b1.y, s1);
    s0 = fmaf(q1.z, a1.z, s0); s1 = fmaf(q1.z, b1.z, s1);
    s0 = fmaf(q1.w, a1.w, s0); s1 = fmaf(q1.w, b1.w, s1);
    s0 = fmaf(q2.x, a2.x, s0); s1 = fmaf(q2.x, b2.x, s1);
    s0 = fmaf(q2.y, a2.y, s0); s1 = fmaf(q2.y, b2.y, s1);
    s0 = fmaf(q2.z, a2.z, s0); s1 = fmaf(q2.z, b2.z, s1);
    s0 = fmaf(q2.w, a2.w, s0); s1 = fmaf(q2.w, b2.w, s1);
    s0 = fmaf(q3.x, a3.x, s0); s1 = fmaf(q3.x, b3.x, s1);
    s0 = fmaf(q3.y, a3.y, s0); s1 = fmaf(q3.y, b3.y, s1);
    s0 = fmaf(q3.z, a3.z, s0); s1 = fmaf(q3.z, b3.z, s1);
    s0 = fmaf(q3.w, a3.w, s0); s1 = fmaf(q3.w, b3.w, s1);
#pragma unroll
    for (int off = 32; off > 0; off >>= 1) {
      s0 += __shfl_xor(s0, off, 64);
      s1 += __shfl_xor(s1, off, 64);
    }
    if (lane == r) myout = s0;
    if (lane == r + 1) myout = s1;
    ins3(s0, row0 + r, v0, i0, v1, i1, v2, i2);
    ins3(s1, row0 + r + 1, v0, i0, v1, i1, v2, i2);
  }
  if (lane < 8) lo[lane] = myout;
  if (lane == 0) {
    cv[wave * 3 + 0] = v0; ci[wave * 3 + 0] = i0;
    cv[wave * 3 + 1] = v1; ci[wave * 3 + 1] = i1;
    cv[wave * 3 + 2] = v2; ci[wave * 3 + 2] = i2;
  }
  __syncthreads();
  if (tid == 0) {
    float w0 = -3.4e38f, w1 = -3.4e38f, w2 = -3.4e38f;
    int j0 = 0x7fffffff, j1 = 0x7fffffff, j2 = 0x7fffffff;
#pragma unroll
    for (int k = 0; k < 12; ++k)
      ins3(cv[k], ci[k], w0, j0, w1, j1, w2, j2);
    candv[blockIdx.x * 3 + 0] = w0; candi[blockIdx.x * 3 + 0] = j0;
    candv[blockIdx.x * 3 + 1] = w1; candi[blockIdx.x * 3 + 1] = j1;
    candv[blockIdx.x * 3 + 2] = w2; candi[blockIdx.x * 3 + 2] = j2;
  }
}

// ---------------------------------------------------------------------------
// Merge 16 chunks' candidates per b -> final top3, sorted ascending.
// 1 block x 64 threads; writes idxi (for next gates gather) + idx (d_out).
// ---------------------------------------------------------------------------
__global__ __launch_bounds__(64) void top3_merge(
    const float* __restrict__ candv, const int* __restrict__ candi,
    float* __restrict__ idx_out, int* __restrict__ idxi)
{
  int b = threadIdx.x;
  float v0 = -3.4e38f, v1 = -3.4e38f, v2 = -3.4e38f;
  int i0 = 0x7fffffff, i1 = 0x7fffffff, i2 = 0x7fffffff;
  const int base = b * 48;
#pragma unroll
  for (int k = 0; k < 48; ++k)
    ins3(candv[base + k], candi[base + k], v0, i0, v1, i1, v2, i2);
  int a = i0, bb = i1, c = i2, tw;
  if (a > bb) { tw = a; a = bb; bb = tw; }
  if (bb > c) { tw = bb; bb = c; c = tw; }
  if (a > bb) { tw = a; a = bb; bb = tw; }
  idxi[b * 3 + 0] = a; idxi[b * 3 + 1] = bb; idxi[b * 3 + 2] = c;
  idx_out[b * 3 + 0] = (float)a;
  idx_out[b * 3 + 1] = (float)bb;
  idx_out[b * 3 + 2] = (float)c;
}

// ---------------------------------------------------------------------------
extern "C" void kernel_launch(void* const* d_in, const int* in_sizes, int n_in,
                              void* d_out, int out_size, void* d_ws, size_t ws_size,
                              hipStream_t stream)
{
  (void)in_sizes; (void)n_in; (void)out_size; (void)ws_size;
  const float* enc   = (const float*)d_in[0];
  const float* h0    = (const float*)d_in[1];
  const float* c0    = (const float*)d_in[2];
  const float* x0    = (const float*)d_in[4];
  const float* W_ih  = (const float*)d_in[6];
  const float* b_ih  = (const float*)d_in[7];
  const float* W_hh  = (const float*)d_in[8];
  const float* b_hh  = (const float*)d_in[9];
  const float* Wqkv  = (const float*)d_in[10];
  const float* bqkv  = (const float*)d_in[11];
  const float* Wout  = (const float*)d_in[12];
  const float* bout  = (const float*)d_in[13];
  const float* Wqt   = (const float*)d_in[14];
  const float* bqt   = (const float*)d_in[15];

  float* ws    = (float*)d_ws;
  float* P     = ws;                          // 8*64*4096 floats
  float* W2    = P + 8 * 64 * 4096;           // 1024*2048
  float* bc    = W2 + 1024 * 2048;            // 1024
  float* hbuf  = bc + 1024;                   // 64*1024
  float* cbuf  = hbuf + 64 * 1024;            // 64*1024
  float* ctx   = cbuf + 64 * 1024;            // 64*1024
  float* Kc    = ctx + 64 * 1024;             // 64*8*24*128
  float* Vc    = Kc + 64 * NH_ * S_ * HD_;
  float* candv = Vc + 64 * NH_ * S_ * HD_;    // 1024*3
  int*   candi = (int*)(candv + 1024 * 3);    // 1024*3
  int*   idxi  = candi + 1024 * 3;            // 192

  float* logits_out = (float*)d_out;                     // [S,B,N]
  float* idx_out    = logits_out + (size_t)S_ * B_ * N_; // [S,B,3] as float

  // once per launch: combined qt weights/bias
  wc_pre<<<dim3(256), dim3(256), 0, stream>>>(Wqt, Wout, bout, bqt, W2, bc);

  for (int t = 0; t < S_; ++t) {
    const float* xin   = (t == 0) ? x0 : nullptr;   // t>0: gather from enc
    const float* hprev = (t == 0) ? h0 : hbuf;
    const float* cprev = (t == 0) ? c0 : cbuf;

    // gates = [x|h] @ [W_ih|W_hh]^T -> P[8][64][4096]
    gemm5<<<dim3(32, 8), dim3(512), 0, stream>>>(
        xin, 3072, W_ih, 3072, 3072,
        hprev, 1024, W_hh, 1024,
        enc, idxi, t > 0, P, 4096, 512);
    lstm_red<<<dim3(64), dim3(256), 0, stream>>>(P, b_ih, b_hh, cprev, hbuf, cbuf);

    // qkv = h @ Wqkv^T -> P[8][64][3072]
    gemm5<<<dim3(24, 8), dim3(512), 0, stream>>>(
        hbuf, 1024, Wqkv, 1024, 1024,
        hbuf, 1024, Wqkv, 1024,
        enc, idxi, 0, P, 3072, 128);
    attn_fused<<<dim3(512), dim3(128), 0, stream>>>(P, bqkv, Kc, Vc, ctx, t);

    // query = [h|ctx] @ W2^T (+bc at reduce) -> P[16][64][1024]
    gemm5<<<dim3(8, 16), dim3(512), 0, stream>>>(
        hbuf, 1024, W2, 2048, 1024,
        ctx, 1024, W2 + 1024, 2048,
        enc, idxi, 0, P, 1024, 128);

    // logits + per-chunk top3, then tiny merge (idxi for next gather + idx out)
    logits4<<<dim3(1024), dim3(256), 0, stream>>>(
        P, bc, enc, logits_out + (size_t)t * B_ * N_, candv, candi);
    top3_merge<<<dim3(1), dim3(64), 0, stream>>>(
        candv, candi, idx_out + (size_t)t * B_ * 3, idxi);
  }
}